// Round 1
// baseline (2501.152 us; speedup 1.0000x reference)
//
#include <hip/hip_runtime.h>
#include <math.h>

constexpr int B   = 2;
constexpr int N   = 2048;
constexpr int HID = 768;
constexpr int H   = 12;
constexpr int D   = 64;
constexpr int M   = B * N;                 // 4096 GEMM rows
constexpr int QKV_ELEMS = B * H * N * D;   // 3,145,728 floats per tensor

// ---------------------------------------------------------------------------
// QKV projection: C[m,o] = sum_c hs[m,c] * W[o,c] + bias[o]
// stored permuted: dst[((b*H + h)*N + i)*D + d]   (m = b*N+i, o = h*D+d)
// grid: (M/64, HID/64, 3)   block: 256
// ---------------------------------------------------------------------------
__global__ __launch_bounds__(256) void qkv_gemm_kernel(
    const float* __restrict__ hs,
    const float* __restrict__ Wq, const float* __restrict__ bq,
    const float* __restrict__ Wk, const float* __restrict__ bk,
    const float* __restrict__ Wv, const float* __restrict__ bv,
    float* __restrict__ Qo, float* __restrict__ Ko, float* __restrict__ Vo)
{
    const int m0 = blockIdx.x * 64;
    const int o0 = blockIdx.y * 64;
    const float* W; const float* bias; float* dst;
    if (blockIdx.z == 0)      { W = Wq; bias = bq; dst = Qo; }
    else if (blockIdx.z == 1) { W = Wk; bias = bk; dst = Ko; }
    else                      { W = Wv; bias = bv; dst = Vo; }

    __shared__ float As[16][65];   // [k][m], +1 pad breaks bank conflicts
    __shared__ float Bs[16][65];   // [k][o]

    const int t  = threadIdx.x;
    const int tm = (t >> 4) * 4;   // 0..60
    const int to = (t & 15) * 4;   // 0..60

    float acc[4][4];
    #pragma unroll
    for (int i = 0; i < 4; i++)
        #pragma unroll
        for (int j = 0; j < 4; j++) acc[i][j] = 0.f;

    const int mm = t >> 2;         // 0..63
    const int k4 = (t & 3) * 4;    // 0,4,8,12

    for (int k0 = 0; k0 < HID; k0 += 16) {
        // stage A (64x16) and W (64x16), K-major in LDS
        float4 a = *(const float4*)&hs[(size_t)(m0 + mm) * HID + k0 + k4];
        As[k4 + 0][mm] = a.x; As[k4 + 1][mm] = a.y;
        As[k4 + 2][mm] = a.z; As[k4 + 3][mm] = a.w;
        float4 w = *(const float4*)&W[(size_t)(o0 + mm) * HID + k0 + k4];
        Bs[k4 + 0][mm] = w.x; Bs[k4 + 1][mm] = w.y;
        Bs[k4 + 2][mm] = w.z; Bs[k4 + 3][mm] = w.w;
        __syncthreads();

        #pragma unroll
        for (int kk = 0; kk < 16; kk++) {
            const float a0 = As[kk][tm + 0], a1 = As[kk][tm + 1],
                        a2 = As[kk][tm + 2], a3 = As[kk][tm + 3];
            const float b0 = Bs[kk][to + 0], b1 = Bs[kk][to + 1],
                        b2 = Bs[kk][to + 2], b3 = Bs[kk][to + 3];
            acc[0][0] = fmaf(a0, b0, acc[0][0]);
            acc[0][1] = fmaf(a0, b1, acc[0][1]);
            acc[0][2] = fmaf(a0, b2, acc[0][2]);
            acc[0][3] = fmaf(a0, b3, acc[0][3]);
            acc[1][0] = fmaf(a1, b0, acc[1][0]);
            acc[1][1] = fmaf(a1, b1, acc[1][1]);
            acc[1][2] = fmaf(a1, b2, acc[1][2]);
            acc[1][3] = fmaf(a1, b3, acc[1][3]);
            acc[2][0] = fmaf(a2, b0, acc[2][0]);
            acc[2][1] = fmaf(a2, b1, acc[2][1]);
            acc[2][2] = fmaf(a2, b2, acc[2][2]);
            acc[2][3] = fmaf(a2, b3, acc[2][3]);
            acc[3][0] = fmaf(a3, b0, acc[3][0]);
            acc[3][1] = fmaf(a3, b1, acc[3][1]);
            acc[3][2] = fmaf(a3, b2, acc[3][2]);
            acc[3][3] = fmaf(a3, b3, acc[3][3]);
        }
        __syncthreads();
    }

    const int o  = o0 + to;        // 4 consecutive outputs, within one head
    const int h  = o >> 6;
    const int d  = o & 63;
    const float bs0 = bias[o + 0], bs1 = bias[o + 1],
                bs2 = bias[o + 2], bs3 = bias[o + 3];
    #pragma unroll
    for (int rr = 0; rr < 4; rr++) {
        const int m = m0 + tm + rr;
        const int b = m >> 11;          // / N
        const int i = m & (N - 1);
        float4 v4 = make_float4(acc[rr][0] + bs0, acc[rr][1] + bs1,
                                acc[rr][2] + bs2, acc[rr][3] + bs3);
        *(float4*)&dst[(((size_t)b * H + h) * N + i) * D + d] = v4;
    }
}

// ---------------------------------------------------------------------------
// Fused relative attention (flash-style, fp32).
// grid: (N/16, H, B)  block: 256.  Each block: 16 query rows, loops 64-key
// tiles with online softmax. Thread mapping: r = t&15 (query row),
// g = t>>4 (16 col-groups of 4 for scores / 16 d-groups of 4 for PV).
// ---------------------------------------------------------------------------
__global__ __launch_bounds__(256) void attn_kernel(
    const float* __restrict__ Q, const float* __restrict__ K,
    const float* __restrict__ V,
    const float* __restrict__ r_emb, const float* __restrict__ r_w_bias,
    const float* __restrict__ r_bias, float* __restrict__ out)
{
    const int i0 = blockIdx.x * 16;
    const int h  = blockIdx.y;
    const int b  = blockIdx.z;

    const float* Qbh = Q + (size_t)(b * H + h) * N * D;
    const float* Kbh = K + (size_t)(b * H + h) * N * D;
    const float* Vbh = V + (size_t)(b * H + h) * N * D;

    __shared__ float qws[16][68];   // q + r_w_bias
    __shared__ float qrs[17][68];   // raw q rows i0..i0+16 (row 16 for shift)
    __shared__ float ks [64][68];   // k tile [c][d]
    __shared__ float vs [64][68];   // v tile [c][d]
    __shared__ float res[80][68];   // r_emb rows indexed by t_rel - tmin
    __shared__ float rbs[80];       // r_bias, same indexing
    __shared__ float Ss [16][68];   // score tile

    const int t = threadIdx.x;
    const int r = t & 15;
    const int g = t >> 4;

    // ---- stage q tiles (16 + 1 rows) ----
    {
        const int row = t >> 4;
        const int d4  = (t & 15) * 4;
        float4 qv = *(const float4*)&Qbh[(size_t)(i0 + row) * D + d4];
        float4 wv = *(const float4*)&r_w_bias[h * D + d4];
        *(float4*)&qws[row][d4] = make_float4(qv.x + wv.x, qv.y + wv.y,
                                              qv.z + wv.z, qv.w + wv.w);
        *(float4*)&qrs[row][d4] = qv;
    }
    if (t < 16) {
        const int d4 = t * 4;
        float4 qv = make_float4(0.f, 0.f, 0.f, 0.f);
        if (i0 + 16 < N) qv = *(const float4*)&Qbh[(size_t)(i0 + 16) * D + d4];
        *(float4*)&qrs[16][d4] = qv;
    }

    float m = -INFINITY;
    float l = 0.f;
    float av[4] = {0.f, 0.f, 0.f, 0.f};

    for (int j0 = 0; j0 < N; j0 += 64) {
        __syncthreads();   // previous tile fully consumed before restaging

        // ---- stage k and v tiles (64x64 each) ----
        #pragma unroll
        for (int e = 0; e < 4; e++) {
            const int idx = t + e * 256;        // float4 index 0..1023
            const int c   = idx >> 4;
            const int d4  = (idx & 15) * 4;
            *(float4*)&ks[c][d4] = *(const float4*)&Kbh[(size_t)(j0 + c) * D + d4];
            *(float4*)&vs[c][d4] = *(const float4*)&Vbh[(size_t)(j0 + c) * D + d4];
        }
        // ---- stage relative-embedding rows for t_rel in [tmin, tmin+79] ----
        // t_rel = j - i;  t_rel<=0 -> re[N-1+t_rel];  ==1 -> zero pad;
        // >=2 -> re[t_rel-2]
        const int tmin = j0 - i0 - 15;
        #pragma unroll
        for (int e = 0; e < 5; e++) {
            const int idx = t + e * 256;        // float4 index 0..1279
            const int w   = idx >> 4;           // 0..79
            const int d4  = (idx & 15) * 4;
            const int tv  = tmin + w;
            float4 rv = make_float4(0.f, 0.f, 0.f, 0.f);
            if (tv != 1) {
                const int src = (tv <= 0) ? (N - 1 + tv) : (tv - 2);
                rv = *(const float4*)&r_emb[((size_t)src * H + h) * D + d4];
            }
            *(float4*)&res[w][d4] = rv;
        }
        if (t < 80) {
            const int tv = tmin + t;
            rbs[t] = (tv == 1) ? 0.f
                   : r_bias[((tv <= 0) ? (N - 1 + tv) : (tv - 2)) * H + h];
        }
        __syncthreads();

        // ---- scores: AC + shifted BD, scaled by 1/sqrt(D) ----
        float sc[4] = {0.f, 0.f, 0.f, 0.f};
        const int c0 = g * 4;
        #pragma unroll
        for (int dk = 0; dk < 64; dk += 4) {
            float4 qv = *(const float4*)&qws[r][dk];
            #pragma unroll
            for (int u = 0; u < 4; u++) {
                float4 kv = *(const float4*)&ks[c0 + u][dk];
                sc[u] = fmaf(qv.x, kv.x, sc[u]);
                sc[u] = fmaf(qv.y, kv.y, sc[u]);
                sc[u] = fmaf(qv.z, kv.z, sc[u]);
                sc[u] = fmaf(qv.w, kv.w, sc[u]);
            }
        }
        #pragma unroll
        for (int u = 0; u < 4; u++) {
            const int c    = c0 + u;
            const int trel = (j0 + c) - (i0 + r);
            if (trel == 1) { sc[u] *= 0.125f; continue; }   // zero-pad element
            const int w = c - r + 15;                       // 0..78
            const float* qrow = (trel >= 2) ? &qrs[r + 1][0] : &qrs[r][0];
            const float* rrow = &res[w][0];
            float bd = rbs[w];
            #pragma unroll
            for (int dk = 0; dk < 64; dk += 4) {
                float4 qv = *(const float4*)&qrow[dk];
                float4 rv = *(const float4*)&rrow[dk];
                bd = fmaf(qv.x, rv.x, bd);
                bd = fmaf(qv.y, rv.y, bd);
                bd = fmaf(qv.z, rv.z, bd);
                bd = fmaf(qv.w, rv.w, bd);
            }
            sc[u] = (sc[u] + bd) * 0.125f;
        }
        *(float4*)&Ss[r][c0] = make_float4(sc[0], sc[1], sc[2], sc[3]);
        __syncthreads();

        // ---- online softmax + PV ----
        // (all 16 threads sharing row r compute identical m/l: same data,
        //  same op order -> deterministic agreement)
        float mt = -INFINITY;
        #pragma unroll
        for (int c = 0; c < 64; c += 4) {
            float4 sv = *(const float4*)&Ss[r][c];
            mt = fmaxf(mt, fmaxf(fmaxf(sv.x, sv.y), fmaxf(sv.z, sv.w)));
        }
        const float mnew  = fmaxf(m, mt);
        const float alpha = __expf(m - mnew);   // m=-inf first tile -> 0
        l *= alpha;
        av[0] *= alpha; av[1] *= alpha; av[2] *= alpha; av[3] *= alpha;
        float lsum = 0.f;
        #pragma unroll
        for (int c = 0; c < 64; c += 4) {
            float4 sv = *(const float4*)&Ss[r][c];
            const float p0 = __expf(sv.x - mnew);
            const float p1 = __expf(sv.y - mnew);
            const float p2 = __expf(sv.z - mnew);
            const float p3 = __expf(sv.w - mnew);
            lsum += (p0 + p1) + (p2 + p3);
            float4 v0 = *(const float4*)&vs[c + 0][g * 4];
            float4 v1 = *(const float4*)&vs[c + 1][g * 4];
            float4 v2 = *(const float4*)&vs[c + 2][g * 4];
            float4 v3 = *(const float4*)&vs[c + 3][g * 4];
            av[0] = fmaf(p0, v0.x, av[0]); av[1] = fmaf(p0, v0.y, av[1]);
            av[2] = fmaf(p0, v0.z, av[2]); av[3] = fmaf(p0, v0.w, av[3]);
            av[0] = fmaf(p1, v1.x, av[0]); av[1] = fmaf(p1, v1.y, av[1]);
            av[2] = fmaf(p1, v1.z, av[2]); av[3] = fmaf(p1, v1.w, av[3]);
            av[0] = fmaf(p2, v2.x, av[0]); av[1] = fmaf(p2, v2.y, av[1]);
            av[2] = fmaf(p2, v2.z, av[2]); av[3] = fmaf(p2, v2.w, av[3]);
            av[0] = fmaf(p3, v3.x, av[0]); av[1] = fmaf(p3, v3.y, av[1]);
            av[2] = fmaf(p3, v3.z, av[2]); av[3] = fmaf(p3, v3.w, av[3]);
        }
        l += lsum;
        m = mnew;
    }

    const float inv = 1.f / l;
    float4 o4 = make_float4(av[0] * inv, av[1] * inv, av[2] * inv, av[3] * inv);
    *(float4*)&out[((size_t)b * N + (i0 + r)) * HID + h * D + g * 4] = o4;
}

// ---------------------------------------------------------------------------
extern "C" void kernel_launch(void* const* d_in, const int* in_sizes, int n_in,
                              void* d_out, int out_size, void* d_ws, size_t ws_size,
                              hipStream_t stream)
{
    (void)in_sizes; (void)n_in; (void)out_size; (void)ws_size;
    const float* hs   = (const float*)d_in[0];
    const float* remb = (const float*)d_in[1];
    const float* rwb  = (const float*)d_in[2];
    const float* rb   = (const float*)d_in[3];
    const float* Wq   = (const float*)d_in[4];
    const float* bq   = (const float*)d_in[5];
    const float* Wk   = (const float*)d_in[6];
    const float* bk   = (const float*)d_in[7];
    const float* Wv   = (const float*)d_in[8];
    const float* bv   = (const float*)d_in[9];
    float* out = (float*)d_out;

    float* Qw = (float*)d_ws;               // [b][h][n][d]
    float* Kw = Qw + QKV_ELEMS;
    float* Vw = Kw + QKV_ELEMS;

    qkv_gemm_kernel<<<dim3(M / 64, HID / 64, 3), 256, 0, stream>>>(
        hs, Wq, bq, Wk, bk, Wv, bv, Qw, Kw, Vw);
    attn_kernel<<<dim3(N / 16, H, B), 256, 0, stream>>>(
        Qw, Kw, Vw, remb, rwb, rb, out);
}

// Round 2
// 641.926 us; speedup vs baseline: 3.8963x; 3.8963x over previous
//
#include <hip/hip_runtime.h>
#include <math.h>

constexpr int B   = 2;
constexpr int N   = 2048;
constexpr int HID = 768;
constexpr int H   = 12;
constexpr int D   = 64;
constexpr int M   = B * N;
constexpr int QKV_ELEMS = B * H * N * D;   // 3,145,728 elems per tensor

typedef __attribute__((ext_vector_type(8))) short s8v;   // 8 x bf16
typedef __attribute__((ext_vector_type(4))) float f4v;   // 4 x f32

__device__ __forceinline__ float bf2f(short u) {
    union { unsigned int i; float f; } v;
    v.i = ((unsigned int)(unsigned short)u) << 16;
    return v.f;
}
__device__ __forceinline__ unsigned short f2bf(float f) {
    union { float f; unsigned int i; } v; v.f = f;
    unsigned int r = v.i + 0x7fff + ((v.i >> 16) & 1);   // RNE
    return (unsigned short)(r >> 16);
}
__device__ __forceinline__ f4v mfma16(s8v a, s8v b, f4v c) {
    return __builtin_amdgcn_mfma_f32_16x16x32_bf16(a, b, c, 0, 0, 0);
}

// ---------------------------------------------------------------------------
// Convert r_emb -> bf16 [h][s][d], r_bias -> f32 [h][s]
// ---------------------------------------------------------------------------
__global__ __launch_bounds__(256) void convert_rel_kernel(
    const float* __restrict__ r_emb, const float* __restrict__ r_bias,
    unsigned short* __restrict__ reb, float* __restrict__ rbt)
{
    const int idx = blockIdx.x * 256 + threadIdx.x;
    if (idx < H * N * D) {
        const int d = idx & 63;
        const int s = (idx >> 6) & (N - 1);
        const int h = idx / (N * D);
        reb[idx] = f2bf(r_emb[((size_t)s * H + h) * D + d]);
    }
    if (idx < H * N) {   // rbt[h][s]
        const int h = idx >> 11;
        const int s = idx & (N - 1);
        rbt[idx] = r_bias[(size_t)s * H + h];
    }
}

// ---------------------------------------------------------------------------
// QKV projection (fp32 vector GEMM, bf16 output).
// Q,K: [b][h][n][d] bf16.  V: TRANSPOSED [b][h][d][n] bf16 (for PV B-frags).
// grid: (M/64, HID/64, 3)   block: 256
// ---------------------------------------------------------------------------
__global__ __launch_bounds__(256) void qkv_gemm_kernel(
    const float* __restrict__ hs,
    const float* __restrict__ Wq, const float* __restrict__ bq,
    const float* __restrict__ Wk, const float* __restrict__ bk,
    const float* __restrict__ Wv, const float* __restrict__ bv,
    unsigned short* __restrict__ Qo, unsigned short* __restrict__ Ko,
    unsigned short* __restrict__ Vt)
{
    const int m0 = blockIdx.x * 64;
    const int o0 = blockIdx.y * 64;
    const float* W; const float* bias;
    if (blockIdx.z == 0)      { W = Wq; bias = bq; }
    else if (blockIdx.z == 1) { W = Wk; bias = bk; }
    else                      { W = Wv; bias = bv; }

    __shared__ float As[16][65];
    __shared__ float Bs[16][65];

    const int t  = threadIdx.x;
    const int tm = (t >> 4) * 4;
    const int to = (t & 15) * 4;

    float acc[4][4];
    #pragma unroll
    for (int i = 0; i < 4; i++)
        #pragma unroll
        for (int j = 0; j < 4; j++) acc[i][j] = 0.f;

    const int mm = t >> 2;
    const int k4 = (t & 3) * 4;

    for (int k0 = 0; k0 < HID; k0 += 16) {
        float4 a = *(const float4*)&hs[(size_t)(m0 + mm) * HID + k0 + k4];
        As[k4 + 0][mm] = a.x; As[k4 + 1][mm] = a.y;
        As[k4 + 2][mm] = a.z; As[k4 + 3][mm] = a.w;
        float4 w = *(const float4*)&W[(size_t)(o0 + mm) * HID + k0 + k4];
        Bs[k4 + 0][mm] = w.x; Bs[k4 + 1][mm] = w.y;
        Bs[k4 + 2][mm] = w.z; Bs[k4 + 3][mm] = w.w;
        __syncthreads();

        #pragma unroll
        for (int kk = 0; kk < 16; kk++) {
            const float a0 = As[kk][tm + 0], a1 = As[kk][tm + 1],
                        a2 = As[kk][tm + 2], a3 = As[kk][tm + 3];
            const float b0 = Bs[kk][to + 0], b1 = Bs[kk][to + 1],
                        b2 = Bs[kk][to + 2], b3 = Bs[kk][to + 3];
            acc[0][0] = fmaf(a0, b0, acc[0][0]);
            acc[0][1] = fmaf(a0, b1, acc[0][1]);
            acc[0][2] = fmaf(a0, b2, acc[0][2]);
            acc[0][3] = fmaf(a0, b3, acc[0][3]);
            acc[1][0] = fmaf(a1, b0, acc[1][0]);
            acc[1][1] = fmaf(a1, b1, acc[1][1]);
            acc[1][2] = fmaf(a1, b2, acc[1][2]);
            acc[1][3] = fmaf(a1, b3, acc[1][3]);
            acc[2][0] = fmaf(a2, b0, acc[2][0]);
            acc[2][1] = fmaf(a2, b1, acc[2][1]);
            acc[2][2] = fmaf(a2, b2, acc[2][2]);
            acc[2][3] = fmaf(a2, b3, acc[2][3]);
            acc[3][0] = fmaf(a3, b0, acc[3][0]);
            acc[3][1] = fmaf(a3, b1, acc[3][1]);
            acc[3][2] = fmaf(a3, b2, acc[3][2]);
            acc[3][3] = fmaf(a3, b3, acc[3][3]);
        }
        __syncthreads();
    }

    const int o = o0 + to;
    const int h = o >> 6;
    const float bs0 = bias[o + 0], bs1 = bias[o + 1],
                bs2 = bias[o + 2], bs3 = bias[o + 3];
    if (blockIdx.z == 2) {
        // V transposed: Vt[((b*H+h)*D + d)*N + i], 4 consecutive i per store
        const int m  = m0 + tm;
        const int bb = m >> 11;
        const int i  = m & (N - 1);
        const float bsv[4] = {bs0, bs1, bs2, bs3};
        #pragma unroll
        for (int cc = 0; cc < 4; cc++) {
            const int d = (o + cc) & 63;
            ushort4 pk;
            pk.x = f2bf(acc[0][cc] + bsv[cc]);
            pk.y = f2bf(acc[1][cc] + bsv[cc]);
            pk.z = f2bf(acc[2][cc] + bsv[cc]);
            pk.w = f2bf(acc[3][cc] + bsv[cc]);
            *(ushort4*)&Vt[(((size_t)bb * H + h) * D + d) * N + i] = pk;
        }
    } else {
        unsigned short* dst = (blockIdx.z == 0) ? Qo : Ko;
        const int d0 = o & 63;
        #pragma unroll
        for (int rr = 0; rr < 4; rr++) {
            const int m  = m0 + tm + rr;
            const int bb = m >> 11;
            const int i  = m & (N - 1);
            ushort4 pk;
            pk.x = f2bf(acc[rr][0] + bs0);
            pk.y = f2bf(acc[rr][1] + bs1);
            pk.z = f2bf(acc[rr][2] + bs2);
            pk.w = f2bf(acc[rr][3] + bs3);
            *(ushort4*)&dst[(((size_t)bb * H + h) * N + i) * D + d0] = pk;
        }
    }
}

// ---------------------------------------------------------------------------
// Fused relative attention, bf16 MFMA, flash-style online softmax.
// grid: (N/64, H, B)  block: 256 (4 waves).  Wave w owns q rows i0+16w..+15.
// Per 64-key tile: AC (8 mfma), BD Sb product (10 mfma + shared row-64 dot),
// LDS gather implementing the rel_shift, softmax, PV (8 mfma).
// ---------------------------------------------------------------------------
__global__ __launch_bounds__(256) void attn_mfma_kernel(
    const unsigned short* __restrict__ Qb, const unsigned short* __restrict__ Kb,
    const unsigned short* __restrict__ Vt, const unsigned short* __restrict__ reb,
    const float* __restrict__ rbt, const float* __restrict__ rwb_g,
    float* __restrict__ out)
{
    const int i0 = blockIdx.x * 64;
    const int h  = blockIdx.y;
    const int b  = blockIdx.z;
    const int bh = b * H + h;

    const unsigned short* Qbh = Qb + (size_t)bh * N * D;
    const unsigned short* Kbh = Kb + (size_t)bh * N * D;
    const unsigned short* Vbh = Vt + (size_t)bh * D * N;   // [d][n]
    const unsigned short* reh = reb + (size_t)h * N * D;   // [s][d]
    const float*          rbh = rbt + (size_t)h * N;

    // LDS layout (byte offsets, all 16B aligned)
    __shared__ __align__(16) char smem[63936];
    unsigned short (*Ks)[72]  = (unsigned short(*)[72])(smem + 0);      // 64x72
    unsigned short (*Vs)[72]  = (unsigned short(*)[72])(smem + 9216);   // [d][key]
    unsigned short (*Res)[72] = (unsigned short(*)[72])(smem + 18432);  // 128x72
    float*          Rb        = (float*)(smem + 36864);                 // 128
    unsigned short (*Sb)[132] = (unsigned short(*)[132])(smem + 37376); // 65x132
    unsigned short (*QL)[72]  = (unsigned short(*)[72])(smem + 54544);  // 64x72 (dies after init)
    unsigned short (*PsAll)[72] = (unsigned short(*)[72])(smem + 54544);// Ps aliases QL
    unsigned short* q64       = (unsigned short*)(smem + 63760);        // 72

    const int t    = threadIdx.x;
    const int lane = t & 63;
    const int w    = t >> 6;
    const int quad = lane >> 4;
    const int col  = lane & 15;
    unsigned short (*Ps)[72] = PsAll + w * 16;

    // ---- stage Q rows i0..i0+63 into QL; row i0+64 into q64 ----
    #pragma unroll
    for (int e = 0; e < 2; e++) {
        const int idx = t + e * 256;          // 0..511
        const int r   = idx >> 3;
        const int d8  = (idx & 7) * 8;
        *(s8v*)&QL[r][d8] = *(const s8v*)&Qbh[(size_t)(i0 + r) * D + d8];
    }
    if (t < 8) {
        const int d8 = t * 8;
        s8v z = {0, 0, 0, 0, 0, 0, 0, 0};
        if (i0 + 64 < N) z = *(const s8v*)&Qbh[(size_t)(i0 + 64) * D + d8];
        *(s8v*)&q64[d8] = z;
    }
    __syncthreads();

    // ---- build A-fragments: raw q (BD) and q + r_w_bias (AC) ----
    s8v qr[2], qw[2];
    #pragma unroll
    for (int ks = 0; ks < 2; ks++) {
        qr[ks] = *(s8v*)&QL[16 * w + col][ks * 32 + quad * 8];
        float4 r0 = *(const float4*)&rwb_g[h * D + ks * 32 + quad * 8];
        float4 r1 = *(const float4*)&rwb_g[h * D + ks * 32 + quad * 8 + 4];
        const float rv[8] = {r0.x, r0.y, r0.z, r0.w, r1.x, r1.y, r1.z, r1.w};
        s8v qq;
        #pragma unroll
        for (int j = 0; j < 8; j++)
            qq[j] = (short)f2bf(bf2f(qr[ks][j]) + rv[j]);
        qw[ks] = qq;
    }

    f4v  Oacc[4];
    #pragma unroll
    for (int dt = 0; dt < 4; dt++) Oacc[dt] = (f4v){0.f, 0.f, 0.f, 0.f};
    float mrow[4] = {-INFINITY, -INFINITY, -INFINITY, -INFINITY};
    float lrow[4] = {0.f, 0.f, 0.f, 0.f};

    const int u0w = 48 - 16 * w;

    for (int j0 = 0; j0 < N; j0 += 64) {
        __syncthreads();   // prior tile fully consumed

        // ---- stage K [key][d] and V^T [d][key] ----
        #pragma unroll
        for (int e = 0; e < 2; e++) {
            const int idx = t + e * 256;
            const int r   = idx >> 3;
            const int d8  = (idx & 7) * 8;
            *(s8v*)&Ks[r][d8] = *(const s8v*)&Kbh[(size_t)(j0 + r) * D + d8];
            *(s8v*)&Vs[r][d8] = *(const s8v*)&Vbh[(size_t)r * N + j0 + d8];
        }
        // ---- stage Res (128 rows) & Rb: u -> t_val = j0-i0-65+u ----
        #pragma unroll
        for (int e = 0; e < 4; e++) {
            const int idx = t + e * 256;          // 0..1023
            const int u   = idx >> 3;
            const int d8  = (idx & 7) * 8;
            int tv  = j0 - i0 - 65 + u;
            int src = (tv < 0) ? tv + N : tv;
            src = (src < 0) ? 0 : ((src > N - 1) ? N - 1 : src);
            *(s8v*)&Res[u][d8] = *(const s8v*)&reh[(size_t)src * D + d8];
        }
        if (t < 128) {
            int tv  = j0 - i0 - 65 + t;
            int src = (tv < 0) ? tv + N : tv;
            src = (src < 0) ? 0 : ((src > N - 1) ? N - 1 : src);
            Rb[t] = rbh[src];
        }
        __syncthreads();

        // ---- AC: Qw @ K^T  (4 n-tiles x 2 k-steps) ----
        f4v acc[4];
        #pragma unroll
        for (int tile = 0; tile < 4; tile++) {
            acc[tile] = (f4v){0.f, 0.f, 0.f, 0.f};
            #pragma unroll
            for (int ks = 0; ks < 2; ks++) {
                s8v kb = *(s8v*)&Ks[tile * 16 + col][ks * 32 + quad * 8];
                acc[tile] = mfma16(qw[ks], kb, acc[tile]);
            }
        }
        // ---- BD: Sb = q @ res^T over this wave's 80-wide u window ----
        #pragma unroll
        for (int tt = 0; tt < 5; tt++) {
            f4v sb = (f4v){0.f, 0.f, 0.f, 0.f};
            #pragma unroll
            for (int ks = 0; ks < 2; ks++) {
                s8v rb8 = *(s8v*)&Res[u0w + tt * 16 + col][ks * 32 + quad * 8];
                sb = mfma16(qr[ks], rb8, sb);
            }
            #pragma unroll
            for (int reg = 0; reg < 4; reg++) {
                const int r = 16 * w + quad * 4 + reg;
                const int u = u0w + tt * 16 + col;
                Sb[r][u] = f2bf(sb[reg] + Rb[u]);
            }
        }
        // ---- Sb row 64 (q[i0+64]) via vector dot, u in [0,64) ----
        if (t < 64) {
            float sum = Rb[t];
            #pragma unroll
            for (int k8 = 0; k8 < 64; k8 += 8) {
                s8v rv = *(s8v*)&Res[t][k8];
                s8v qv = *(s8v*)&q64[k8];
                #pragma unroll
                for (int j = 0; j < 8; j++)
                    sum += bf2f(qv[j]) * bf2f(rv[j]);
            }
            Sb[64][t] = f2bf(sum);
        }
        __syncthreads();

        // ---- gather (rel_shift) + online softmax ----
        float p[4][4];
        float tmax[4] = {-INFINITY, -INFINITY, -INFINITY, -INFINITY};
        #pragma unroll
        for (int tile = 0; tile < 4; tile++) {
            #pragma unroll
            for (int reg = 0; reg < 4; reg++) {
                const int rowg = 16 * w + quad * 4 + reg;
                const int cp   = tile * 16 + col;
                const int trel = (j0 + cp) - (i0 + rowg);
                float s = acc[tile][reg];
                if (trel != 1) {
                    const int rho = rowg + (trel >= 2 ? 1 : 0);
                    const int u   = cp - rho + 64;
                    s += bf2f((short)Sb[rho][u]);
                }
                s *= 0.125f;
                p[tile][reg] = s;
                tmax[reg] = fmaxf(tmax[reg], s);
            }
        }
        #pragma unroll
        for (int reg = 0; reg < 4; reg++) {
            #pragma unroll
            for (int msk = 1; msk < 16; msk <<= 1)
                tmax[reg] = fmaxf(tmax[reg], __shfl_xor(tmax[reg], msk, 64));
            const float mnew  = fmaxf(mrow[reg], tmax[reg]);
            const float alpha = __expf(mrow[reg] - mnew);
            mrow[reg] = mnew;
            lrow[reg] *= alpha;
            #pragma unroll
            for (int dt = 0; dt < 4; dt++) Oacc[dt][reg] *= alpha;
        }
        float lsum[4] = {0.f, 0.f, 0.f, 0.f};
        #pragma unroll
        for (int tile = 0; tile < 4; tile++) {
            #pragma unroll
            for (int reg = 0; reg < 4; reg++) {
                const float e = __expf(p[tile][reg] - mrow[reg]);
                p[tile][reg] = e;
                lsum[reg] += e;
            }
        }
        #pragma unroll
        for (int reg = 0; reg < 4; reg++) {
            #pragma unroll
            for (int msk = 1; msk < 16; msk <<= 1)
                lsum[reg] += __shfl_xor(lsum[reg], msk, 64);
            lrow[reg] += lsum[reg];
        }
        // ---- write P (wave-private LDS region) ----
        #pragma unroll
        for (int tile = 0; tile < 4; tile++)
            #pragma unroll
            for (int reg = 0; reg < 4; reg++)
                Ps[quad * 4 + reg][tile * 16 + col] = f2bf(p[tile][reg]);
        __asm__ volatile("s_waitcnt lgkmcnt(0)" ::: "memory");
        // ---- PV: O += P @ V  (4 d-tiles x 2 k-steps) ----
        #pragma unroll
        for (int dt = 0; dt < 4; dt++) {
            #pragma unroll
            for (int ks = 0; ks < 2; ks++) {
                s8v pf = *(s8v*)&Ps[col][ks * 32 + quad * 8];
                s8v vf = *(s8v*)&Vs[dt * 16 + col][ks * 32 + quad * 8];
                Oacc[dt] = mfma16(pf, vf, Oacc[dt]);
            }
        }
    }

    // ---- epilogue ----
    #pragma unroll
    for (int reg = 0; reg < 4; reg++) {
        const float inv = 1.f / lrow[reg];
        const int row = i0 + 16 * w + quad * 4 + reg;
        const size_t base = ((size_t)b * N + row) * HID + h * D;
        #pragma unroll
        for (int dt = 0; dt < 4; dt++)
            out[base + dt * 16 + col] = Oacc[dt][reg] * inv;
    }
}

// ---------------------------------------------------------------------------
extern "C" void kernel_launch(void* const* d_in, const int* in_sizes, int n_in,
                              void* d_out, int out_size, void* d_ws, size_t ws_size,
                              hipStream_t stream)
{
    (void)in_sizes; (void)n_in; (void)out_size; (void)ws_size;
    const float* hs   = (const float*)d_in[0];
    const float* remb = (const float*)d_in[1];
    const float* rwb  = (const float*)d_in[2];
    const float* rb   = (const float*)d_in[3];
    const float* Wq   = (const float*)d_in[4];
    const float* bq   = (const float*)d_in[5];
    const float* Wk   = (const float*)d_in[6];
    const float* bk   = (const float*)d_in[7];
    const float* Wv   = (const float*)d_in[8];
    const float* bv   = (const float*)d_in[9];
    float* out = (float*)d_out;

    unsigned short* Qb  = (unsigned short*)d_ws;
    unsigned short* Kb  = Qb + QKV_ELEMS;
    unsigned short* Vt  = Kb + QKV_ELEMS;
    unsigned short* reb = Vt + QKV_ELEMS;
    float*          rbt = (float*)(reb + H * N * D);

    convert_rel_kernel<<<(H * N * D + 255) / 256, 256, 0, stream>>>(
        remb, rb, reb, rbt);
    qkv_gemm_kernel<<<dim3(M / 64, HID / 64, 3), 256, 0, stream>>>(
        hs, Wq, bq, Wk, bk, Wv, bv, Qb, Kb, Vt);
    attn_mfma_kernel<<<dim3(N / 64, H, B), 256, 0, stream>>>(
        Qb, Kb, Vt, reb, rbt, rwb, out);
}

// Round 3
// 390.252 us; speedup vs baseline: 6.4091x; 1.6449x over previous
//
#include <hip/hip_runtime.h>
#include <math.h>

constexpr int B   = 2;
constexpr int N   = 2048;
constexpr int HID = 768;
constexpr int H   = 12;
constexpr int D   = 64;
constexpr int M   = B * N;
constexpr int QKV_ELEMS = B * H * N * D;   // 3,145,728 elems per tensor

typedef __attribute__((ext_vector_type(8))) short s8v;            // 8 x bf16
typedef __attribute__((ext_vector_type(8))) unsigned short u8v;   // 8 x u16
typedef __attribute__((ext_vector_type(4))) float f4v;            // 4 x f32
typedef unsigned short ushort_t;

__device__ __forceinline__ float bf2f(short u) {
    union { unsigned int i; float f; } v;
    v.i = ((unsigned int)(unsigned short)u) << 16;
    return v.f;
}
__device__ __forceinline__ unsigned short f2bf(float f) {
    union { float f; unsigned int i; } v; v.f = f;
    unsigned int r = v.i + 0x7fff + ((v.i >> 16) & 1);   // RNE
    return (unsigned short)(r >> 16);
}
__device__ __forceinline__ f4v mfma16(s8v a, s8v b, f4v c) {
    return __builtin_amdgcn_mfma_f32_16x16x32_bf16(a, b, c, 0, 0, 0);
}
__device__ __forceinline__ void gl2lds16(const void* g, void* l) {
    __builtin_amdgcn_global_load_lds(
        (const __attribute__((address_space(1))) void*)g,
        (__attribute__((address_space(3))) void*)l, 16, 0, 0);
}
__device__ __forceinline__ u8v cvt8(const float* src) {
    float4 a = *(const float4*)src;
    float4 b = *(const float4*)(src + 4);
    u8v o;
    o[0] = f2bf(a.x); o[1] = f2bf(a.y); o[2] = f2bf(a.z); o[3] = f2bf(a.w);
    o[4] = f2bf(b.x); o[5] = f2bf(b.y); o[6] = f2bf(b.z); o[7] = f2bf(b.w);
    return o;
}

// ---------------------------------------------------------------------------
// Convert everything to bf16 / repack:
//   hs   -> hsb  [M][768] bf16
//   Wq/Wk/Wv -> Wb [3][768][768] bf16
//   r_emb -> reb [h][s][d] bf16 (permuted)
//   r_bias -> rbt [h][s] f32 (transposed)
// ---------------------------------------------------------------------------
constexpr int CVT_C0 = M * HID / 8;            // 393216
constexpr int CVT_C1 = CVT_C0 + 3 * HID * HID / 8;   // +221184 = 614400
constexpr int CVT_C2 = CVT_C1 + H * N * D / 8;       // +196608 = 811008
constexpr int CVT_C3 = CVT_C2 + H * N;               // +24576  = 835584

__global__ __launch_bounds__(256) void convert_kernel(
    const float* __restrict__ hs,
    const float* __restrict__ Wq, const float* __restrict__ Wk,
    const float* __restrict__ Wv,
    const float* __restrict__ r_emb, const float* __restrict__ r_bias,
    ushort_t* __restrict__ hsb, ushort_t* __restrict__ Wb,
    ushort_t* __restrict__ reb, float* __restrict__ rbt)
{
    const int idx = blockIdx.x * 256 + threadIdx.x;
    if (idx < CVT_C0) {
        *(u8v*)&hsb[(size_t)idx * 8] = cvt8(&hs[(size_t)idx * 8]);
    } else if (idx < CVT_C1) {
        const int j  = idx - CVT_C0;
        const int z  = j / (HID * HID / 8);
        const int jj = j - z * (HID * HID / 8);
        const float* W = (z == 0) ? Wq : ((z == 1) ? Wk : Wv);
        *(u8v*)&Wb[(size_t)z * HID * HID + (size_t)jj * 8] =
            cvt8(&W[(size_t)jj * 8]);
    } else if (idx < CVT_C2) {
        const int k  = idx - CVT_C1;           // chunk over [h][s][d8]
        const int d0 = (k & 7) * 8;
        const int s  = (k >> 3) & (N - 1);
        const int h  = k >> 14;
        *(u8v*)&reb[(size_t)k * 8] = cvt8(&r_emb[((size_t)s * H + h) * D + d0]);
    } else if (idx < CVT_C3) {
        const int j = idx - CVT_C2;
        const int h = j >> 11;
        const int s = j & (N - 1);
        rbt[j] = r_bias[(size_t)s * H + h];
    }
}

// ---------------------------------------------------------------------------
// QKV projection, bf16 MFMA. 128x128 block tile, 4 waves x (64x64), BK=64.
// global_load_lds (16B) staging with XOR-swizzled LDS columns.
// z=0,1 (Q,K): D rows = o  -> ushort4 stores along d into [b][h][n][d]
// z=2   (V)  : D rows = m  -> ushort4 stores along n into [b][h][d][n]
// grid: (M/128, 768/128, 3)  block: 256
// ---------------------------------------------------------------------------
__global__ __launch_bounds__(256) void qkv_mfma_kernel(
    const ushort_t* __restrict__ hsb, const ushort_t* __restrict__ Wb,
    const float* __restrict__ bq, const float* __restrict__ bk,
    const float* __restrict__ bv,
    ushort_t* __restrict__ Qo, ushort_t* __restrict__ Ko,
    ushort_t* __restrict__ Vt)
{
    const int z  = blockIdx.z;
    const int m0 = blockIdx.x * 128;
    const int o0 = blockIdx.y * 128;
    const ushort_t* Wz = Wb + (size_t)z * HID * HID;
    const float* bias = (z == 0) ? bq : ((z == 1) ? bk : bv);

    __shared__ ushort_t Ah[128 * 64];   // hs tile, row-major, col8 ^= row&7
    __shared__ ushort_t Wh[128 * 64];   // W tile, same layout

    const int t    = threadIdx.x;
    const int lane = t & 63;
    const int w    = t >> 6;
    const int quad = lane >> 4;
    const int col  = lane & 15;
    const int x0   = (w >> 1) * 64;    // X-row (D-row) wave offset
    const int y0   = (w & 1) * 64;     // Y-col wave offset

    // X provides D-rows, Y provides D-cols.
    const ushort_t* Xs = (z == 2) ? Ah : Wh;
    const ushort_t* Ys = (z == 2) ? Wh : Ah;

    f4v acc[16];
    #pragma unroll
    for (int i = 0; i < 16; i++) acc[i] = (f4v){0.f, 0.f, 0.f, 0.f};

    const int srow = w * 32 + (lane >> 3);     // staging row base (+e*8)
    const int scol = lane & 7;

    for (int k0 = 0; k0 < HID; k0 += 64) {
        __syncthreads();
        #pragma unroll
        for (int e = 0; e < 4; e++) {
            const int row = srow + e * 8;
            const int c8  = scol ^ (row & 7);
            gl2lds16(&hsb[(size_t)(m0 + row) * HID + k0 + c8 * 8],
                     (void*)&Ah[(w * 32 + e * 8) * 64]);
            gl2lds16(&Wz[(size_t)(o0 + row) * HID + k0 + c8 * 8],
                     (void*)&Wh[(w * 32 + e * 8) * 64]);
        }
        __syncthreads();

        #pragma unroll
        for (int ks = 0; ks < 2; ks++) {
            s8v xf[4], yf[4];
            #pragma unroll
            for (int tt = 0; tt < 4; tt++) {
                const int xr  = x0 + tt * 16 + col;
                const int xc8 = (ks * 4 + quad) ^ (xr & 7);
                xf[tt] = *(const s8v*)&Xs[xr * 64 + xc8 * 8];
                const int yr  = y0 + tt * 16 + col;
                const int yc8 = (ks * 4 + quad) ^ (yr & 7);
                yf[tt] = *(const s8v*)&Ys[yr * 64 + yc8 * 8];
            }
            #pragma unroll
            for (int xt = 0; xt < 4; xt++)
                #pragma unroll
                for (int yt = 0; yt < 4; yt++)
                    acc[xt * 4 + yt] = mfma16(xf[xt], yf[yt], acc[xt * 4 + yt]);
        }
    }

    if (z < 2) {
        ushort_t* dst = (z == 0) ? Qo : Ko;
        #pragma unroll
        for (int xt = 0; xt < 4; xt++) {
            const int ob = o0 + x0 + xt * 16 + quad * 4;  // 4 consecutive o
            const int h  = ob >> 6;
            const int d0 = ob & 63;
            const float4 bv4 = *(const float4*)&bias[ob];
            #pragma unroll
            for (int yt = 0; yt < 4; yt++) {
                const int m  = m0 + y0 + yt * 16 + col;
                const int bb = m >> 11;
                const int ii = m & (N - 1);
                f4v a = acc[xt * 4 + yt];
                ushort4 pk;
                pk.x = f2bf(a[0] + bv4.x);
                pk.y = f2bf(a[1] + bv4.y);
                pk.z = f2bf(a[2] + bv4.z);
                pk.w = f2bf(a[3] + bv4.w);
                *(ushort4*)&dst[(((size_t)bb * H + h) * N + ii) * D + d0] = pk;
            }
        }
    } else {
        #pragma unroll
        for (int yt = 0; yt < 4; yt++) {
            const int o = o0 + y0 + yt * 16 + col;
            const int h = o >> 6;
            const int d = o & 63;
            const float bs = bias[o];
            #pragma unroll
            for (int xt = 0; xt < 4; xt++) {
                const int m  = m0 + x0 + xt * 16 + quad * 4;  // 4 consecutive i
                const int bb = m >> 11;
                const int ib = m & (N - 1);
                f4v a = acc[xt * 4 + yt];
                ushort4 pk;
                pk.x = f2bf(a[0] + bs);
                pk.y = f2bf(a[1] + bs);
                pk.z = f2bf(a[2] + bs);
                pk.w = f2bf(a[3] + bs);
                *(ushort4*)&Vt[(((size_t)bb * H + h) * D + d) * N + ib] = pk;
            }
        }
    }
}

// ---------------------------------------------------------------------------
// Fused relative attention, bf16 MFMA, flash-style online softmax.
// grid: (N/64, H, B)  block: 256 (4 waves).  Wave w owns q rows i0+16w..+15.
// ---------------------------------------------------------------------------
__global__ __launch_bounds__(256) void attn_mfma_kernel(
    const ushort_t* __restrict__ Qb, const ushort_t* __restrict__ Kb,
    const ushort_t* __restrict__ Vt, const ushort_t* __restrict__ reb,
    const float* __restrict__ rbt, const float* __restrict__ rwb_g,
    float* __restrict__ out)
{
    const int i0 = blockIdx.x * 64;
    const int h  = blockIdx.y;
    const int b  = blockIdx.z;
    const int bh = b * H + h;

    const ushort_t* Qbh = Qb + (size_t)bh * N * D;
    const ushort_t* Kbh = Kb + (size_t)bh * N * D;
    const ushort_t* Vbh = Vt + (size_t)bh * D * N;   // [d][n]
    const ushort_t* reh = reb + (size_t)h * N * D;   // [s][d]
    const float*    rbh = rbt + (size_t)h * N;

    __shared__ __align__(16) char smem[63936];
    ushort_t (*Ks)[72]  = (ushort_t(*)[72])(smem + 0);      // 64x72
    ushort_t (*Vs)[72]  = (ushort_t(*)[72])(smem + 9216);   // [d][key]
    ushort_t (*Res)[72] = (ushort_t(*)[72])(smem + 18432);  // 128x72
    float*    Rb        = (float*)(smem + 36864);           // 128
    ushort_t (*Sb)[132] = (ushort_t(*)[132])(smem + 37376); // 65x132
    ushort_t (*QL)[72]  = (ushort_t(*)[72])(smem + 54544);  // 64x72
    ushort_t (*PsAll)[72] = (ushort_t(*)[72])(smem + 54544);
    ushort_t* q64       = (ushort_t*)(smem + 63760);        // 72

    const int t    = threadIdx.x;
    const int lane = t & 63;
    const int w    = t >> 6;
    const int quad = lane >> 4;
    const int col  = lane & 15;
    ushort_t (*Ps)[72] = PsAll + w * 16;

    #pragma unroll
    for (int e = 0; e < 2; e++) {
        const int idx = t + e * 256;
        const int r   = idx >> 3;
        const int d8  = (idx & 7) * 8;
        *(s8v*)&QL[r][d8] = *(const s8v*)&Qbh[(size_t)(i0 + r) * D + d8];
    }
    if (t < 8) {
        const int d8 = t * 8;
        s8v zv = {0, 0, 0, 0, 0, 0, 0, 0};
        if (i0 + 64 < N) zv = *(const s8v*)&Qbh[(size_t)(i0 + 64) * D + d8];
        *(s8v*)&q64[d8] = zv;
    }
    __syncthreads();

    s8v qr[2], qw[2];
    #pragma unroll
    for (int ks = 0; ks < 2; ks++) {
        qr[ks] = *(s8v*)&QL[16 * w + col][ks * 32 + quad * 8];
        float4 r0 = *(const float4*)&rwb_g[h * D + ks * 32 + quad * 8];
        float4 r1 = *(const float4*)&rwb_g[h * D + ks * 32 + quad * 8 + 4];
        const float rv[8] = {r0.x, r0.y, r0.z, r0.w, r1.x, r1.y, r1.z, r1.w};
        s8v qq;
        #pragma unroll
        for (int j = 0; j < 8; j++)
            qq[j] = (short)f2bf(bf2f(qr[ks][j]) + rv[j]);
        qw[ks] = qq;
    }

    f4v Oacc[4];
    #pragma unroll
    for (int dt = 0; dt < 4; dt++) Oacc[dt] = (f4v){0.f, 0.f, 0.f, 0.f};
    float mrow[4] = {-INFINITY, -INFINITY, -INFINITY, -INFINITY};
    float lrow[4] = {0.f, 0.f, 0.f, 0.f};

    const int u0w = 48 - 16 * w;

    for (int j0 = 0; j0 < N; j0 += 64) {
        __syncthreads();

        #pragma unroll
        for (int e = 0; e < 2; e++) {
            const int idx = t + e * 256;
            const int r   = idx >> 3;
            const int d8  = (idx & 7) * 8;
            *(s8v*)&Ks[r][d8] = *(const s8v*)&Kbh[(size_t)(j0 + r) * D + d8];
            *(s8v*)&Vs[r][d8] = *(const s8v*)&Vbh[(size_t)r * N + j0 + d8];
        }
        #pragma unroll
        for (int e = 0; e < 4; e++) {
            const int idx = t + e * 256;
            const int u   = idx >> 3;
            const int d8  = (idx & 7) * 8;
            int tv  = j0 - i0 - 65 + u;
            int src = (tv < 0) ? tv + N : tv;
            src = (src < 0) ? 0 : ((src > N - 1) ? N - 1 : src);
            *(s8v*)&Res[u][d8] = *(const s8v*)&reh[(size_t)src * D + d8];
        }
        if (t < 128) {
            int tv  = j0 - i0 - 65 + t;
            int src = (tv < 0) ? tv + N : tv;
            src = (src < 0) ? 0 : ((src > N - 1) ? N - 1 : src);
            Rb[t] = rbh[src];
        }
        __syncthreads();

        f4v acc[4];
        #pragma unroll
        for (int tile = 0; tile < 4; tile++) {
            acc[tile] = (f4v){0.f, 0.f, 0.f, 0.f};
            #pragma unroll
            for (int ks = 0; ks < 2; ks++) {
                s8v kb = *(s8v*)&Ks[tile * 16 + col][ks * 32 + quad * 8];
                acc[tile] = mfma16(qw[ks], kb, acc[tile]);
            }
        }
        #pragma unroll
        for (int tt = 0; tt < 5; tt++) {
            f4v sb = (f4v){0.f, 0.f, 0.f, 0.f};
            #pragma unroll
            for (int ks = 0; ks < 2; ks++) {
                s8v rb8 = *(s8v*)&Res[u0w + tt * 16 + col][ks * 32 + quad * 8];
                sb = mfma16(qr[ks], rb8, sb);
            }
            #pragma unroll
            for (int reg = 0; reg < 4; reg++) {
                const int r = 16 * w + quad * 4 + reg;
                const int u = u0w + tt * 16 + col;
                Sb[r][u] = f2bf(sb[reg] + Rb[u]);
            }
        }
        if (t < 64) {
            float sum = Rb[t];
            #pragma unroll
            for (int k8 = 0; k8 < 64; k8 += 8) {
                s8v rv = *(s8v*)&Res[t][k8];
                s8v qv = *(s8v*)&q64[k8];
                #pragma unroll
                for (int j = 0; j < 8; j++)
                    sum += bf2f(qv[j]) * bf2f(rv[j]);
            }
            Sb[64][t] = f2bf(sum);
        }
        __syncthreads();

        float p[4][4];
        float tmax[4] = {-INFINITY, -INFINITY, -INFINITY, -INFINITY};
        #pragma unroll
        for (int tile = 0; tile < 4; tile++) {
            #pragma unroll
            for (int reg = 0; reg < 4; reg++) {
                const int rowg = 16 * w + quad * 4 + reg;
                const int cp   = tile * 16 + col;
                const int trel = (j0 + cp) - (i0 + rowg);
                float s = acc[tile][reg];
                if (trel != 1) {
                    const int rho = rowg + (trel >= 2 ? 1 : 0);
                    const int u   = cp - rho + 64;
                    s += bf2f((short)Sb[rho][u]);
                }
                s *= 0.125f;
                p[tile][reg] = s;
                tmax[reg] = fmaxf(tmax[reg], s);
            }
        }
        #pragma unroll
        for (int reg = 0; reg < 4; reg++) {
            #pragma unroll
            for (int msk = 1; msk < 16; msk <<= 1)
                tmax[reg] = fmaxf(tmax[reg], __shfl_xor(tmax[reg], msk, 64));
            const float mnew  = fmaxf(mrow[reg], tmax[reg]);
            const float alpha = __expf(mrow[reg] - mnew);
            mrow[reg] = mnew;
            lrow[reg] *= alpha;
            #pragma unroll
            for (int dt = 0; dt < 4; dt++) Oacc[dt][reg] *= alpha;
        }
        float lsum[4] = {0.f, 0.f, 0.f, 0.f};
        #pragma unroll
        for (int tile = 0; tile < 4; tile++) {
            #pragma unroll
            for (int reg = 0; reg < 4; reg++) {
                const float e = __expf(p[tile][reg] - mrow[reg]);
                p[tile][reg] = e;
                lsum[reg] += e;
            }
        }
        #pragma unroll
        for (int reg = 0; reg < 4; reg++) {
            #pragma unroll
            for (int msk = 1; msk < 16; msk <<= 1)
                lsum[reg] += __shfl_xor(lsum[reg], msk, 64);
            lrow[reg] += lsum[reg];
        }
        #pragma unroll
        for (int tile = 0; tile < 4; tile++)
            #pragma unroll
            for (int reg = 0; reg < 4; reg++)
                Ps[quad * 4 + reg][tile * 16 + col] = f2bf(p[tile][reg]);
        __asm__ volatile("s_waitcnt lgkmcnt(0)" ::: "memory");
        #pragma unroll
        for (int dt = 0; dt < 4; dt++) {
            #pragma unroll
            for (int ks = 0; ks < 2; ks++) {
                s8v pf = *(s8v*)&Ps[col][ks * 32 + quad * 8];
                s8v vf = *(s8v*)&Vs[dt * 16 + col][ks * 32 + quad * 8];
                Oacc[dt] = mfma16(pf, vf, Oacc[dt]);
            }
        }
    }

    #pragma unroll
    for (int reg = 0; reg < 4; reg++) {
        const float inv = 1.f / lrow[reg];
        const int row = i0 + 16 * w + quad * 4 + reg;
        const size_t base = ((size_t)b * N + row) * HID + h * D;
        #pragma unroll
        for (int dt = 0; dt < 4; dt++)
            out[base + dt * 16 + col] = Oacc[dt][reg] * inv;
    }
}

// ---------------------------------------------------------------------------
extern "C" void kernel_launch(void* const* d_in, const int* in_sizes, int n_in,
                              void* d_out, int out_size, void* d_ws, size_t ws_size,
                              hipStream_t stream)
{
    (void)in_sizes; (void)n_in; (void)out_size; (void)ws_size;
    const float* hs   = (const float*)d_in[0];
    const float* remb = (const float*)d_in[1];
    const float* rwb  = (const float*)d_in[2];
    const float* rb   = (const float*)d_in[3];
    const float* Wq   = (const float*)d_in[4];
    const float* bq   = (const float*)d_in[5];
    const float* Wk   = (const float*)d_in[6];
    const float* bk   = (const float*)d_in[7];
    const float* Wv   = (const float*)d_in[8];
    const float* bv   = (const float*)d_in[9];
    float* out = (float*)d_out;

    ushort_t* Qb  = (ushort_t*)d_ws;
    ushort_t* Kb  = Qb + QKV_ELEMS;
    ushort_t* Vt  = Kb + QKV_ELEMS;
    ushort_t* reb = Vt + QKV_ELEMS;
    float*    rbt = (float*)(reb + H * N * D);
    ushort_t* hsb = (ushort_t*)(rbt + H * N);
    ushort_t* Wb  = hsb + (size_t)M * HID;

    convert_kernel<<<CVT_C3 / 256, 256, 0, stream>>>(
        hs, Wq, Wk, Wv, remb, rb, hsb, Wb, reb, rbt);
    qkv_mfma_kernel<<<dim3(M / 128, HID / 128, 3), 256, 0, stream>>>(
        hsb, Wb, bq, bk, bv, Qb, Kb, Vt);
    attn_mfma_kernel<<<dim3(N / 64, H, B), 256, 0, stream>>>(
        Qb, Kb, Vt, reb, rbt, rwb, out);
}

// Round 4
// 309.354 us; speedup vs baseline: 8.0851x; 1.2615x over previous
//
#include <hip/hip_runtime.h>
#include <math.h>

constexpr int B   = 2;
constexpr int N   = 2048;
constexpr int HID = 768;
constexpr int H   = 12;
constexpr int D   = 64;
constexpr int M   = B * N;
constexpr int QKV_ELEMS = B * H * N * D;   // 3,145,728 elems per tensor

typedef __attribute__((ext_vector_type(8))) short s8v;            // 8 x bf16
typedef __attribute__((ext_vector_type(8))) unsigned short u8v;   // 8 x u16
typedef __attribute__((ext_vector_type(4))) float f4v;            // 4 x f32
typedef unsigned short ushort_t;

__device__ __forceinline__ float bf2f(short u) {
    union { unsigned int i; float f; } v;
    v.i = ((unsigned int)(unsigned short)u) << 16;
    return v.f;
}
__device__ __forceinline__ unsigned short f2bf(float f) {
    union { float f; unsigned int i; } v; v.f = f;
    unsigned int r = v.i + 0x7fff + ((v.i >> 16) & 1);   // RNE
    return (unsigned short)(r >> 16);
}
__device__ __forceinline__ f4v mfma16(s8v a, s8v b, f4v c) {
    return __builtin_amdgcn_mfma_f32_16x16x32_bf16(a, b, c, 0, 0, 0);
}
__device__ __forceinline__ void gl2lds16(const void* g, void* l) {
    __builtin_amdgcn_global_load_lds(
        (const __attribute__((address_space(1))) void*)g,
        (__attribute__((address_space(3))) void*)l, 16, 0, 0);
}
__device__ __forceinline__ u8v cvt8(const float* src) {
    float4 a = *(const float4*)src;
    float4 b = *(const float4*)(src + 4);
    u8v o;
    o[0] = f2bf(a.x); o[1] = f2bf(a.y); o[2] = f2bf(a.z); o[3] = f2bf(a.w);
    o[4] = f2bf(b.x); o[5] = f2bf(b.y); o[6] = f2bf(b.z); o[7] = f2bf(b.w);
    return o;
}
__device__ __forceinline__ int clampsrc(int tv) {
    int src = (tv < 0) ? tv + N : tv;
    return (src < 0) ? 0 : ((src > N - 1) ? N - 1 : src);
}

// ---------------------------------------------------------------------------
// Convert everything to bf16 / repack.
// ---------------------------------------------------------------------------
constexpr int CVT_C0 = M * HID / 8;
constexpr int CVT_C1 = CVT_C0 + 3 * HID * HID / 8;
constexpr int CVT_C2 = CVT_C1 + H * N * D / 8;
constexpr int CVT_C3 = CVT_C2 + H * N;

__global__ __launch_bounds__(256) void convert_kernel(
    const float* __restrict__ hs,
    const float* __restrict__ Wq, const float* __restrict__ Wk,
    const float* __restrict__ Wv,
    const float* __restrict__ r_emb, const float* __restrict__ r_bias,
    ushort_t* __restrict__ hsb, ushort_t* __restrict__ Wb,
    ushort_t* __restrict__ reb, float* __restrict__ rbt)
{
    const int idx = blockIdx.x * 256 + threadIdx.x;
    if (idx < CVT_C0) {
        *(u8v*)&hsb[(size_t)idx * 8] = cvt8(&hs[(size_t)idx * 8]);
    } else if (idx < CVT_C1) {
        const int j  = idx - CVT_C0;
        const int z  = j / (HID * HID / 8);
        const int jj = j - z * (HID * HID / 8);
        const float* W = (z == 0) ? Wq : ((z == 1) ? Wk : Wv);
        *(u8v*)&Wb[(size_t)z * HID * HID + (size_t)jj * 8] =
            cvt8(&W[(size_t)jj * 8]);
    } else if (idx < CVT_C2) {
        const int k  = idx - CVT_C1;
        const int d0 = (k & 7) * 8;
        const int s  = (k >> 3) & (N - 1);
        const int h  = k >> 14;
        *(u8v*)&reb[(size_t)k * 8] = cvt8(&r_emb[((size_t)s * H + h) * D + d0]);
    } else if (idx < CVT_C3) {
        const int j = idx - CVT_C2;
        const int h = j >> 11;
        const int s = j & (N - 1);
        rbt[j] = r_bias[(size_t)s * H + h];
    }
}

// ---------------------------------------------------------------------------
// QKV projection, bf16 MFMA (unchanged from round 3).
// ---------------------------------------------------------------------------
__global__ __launch_bounds__(256) void qkv_mfma_kernel(
    const ushort_t* __restrict__ hsb, const ushort_t* __restrict__ Wb,
    const float* __restrict__ bq, const float* __restrict__ bk,
    const float* __restrict__ bv,
    ushort_t* __restrict__ Qo, ushort_t* __restrict__ Ko,
    ushort_t* __restrict__ Vt)
{
    const int z  = blockIdx.z;
    const int m0 = blockIdx.x * 128;
    const int o0 = blockIdx.y * 128;
    const ushort_t* Wz = Wb + (size_t)z * HID * HID;
    const float* bias = (z == 0) ? bq : ((z == 1) ? bk : bv);

    __shared__ ushort_t Ah[128 * 64];
    __shared__ ushort_t Wh[128 * 64];

    const int t    = threadIdx.x;
    const int lane = t & 63;
    const int w    = t >> 6;
    const int quad = lane >> 4;
    const int col  = lane & 15;
    const int x0   = (w >> 1) * 64;
    const int y0   = (w & 1) * 64;

    const ushort_t* Xs = (z == 2) ? Ah : Wh;
    const ushort_t* Ys = (z == 2) ? Wh : Ah;

    f4v acc[16];
    #pragma unroll
    for (int i = 0; i < 16; i++) acc[i] = (f4v){0.f, 0.f, 0.f, 0.f};

    const int srow = w * 32 + (lane >> 3);
    const int scol = lane & 7;

    for (int k0 = 0; k0 < HID; k0 += 64) {
        __syncthreads();
        #pragma unroll
        for (int e = 0; e < 4; e++) {
            const int row = srow + e * 8;
            const int c8  = scol ^ (row & 7);
            gl2lds16(&hsb[(size_t)(m0 + row) * HID + k0 + c8 * 8],
                     (void*)&Ah[(w * 32 + e * 8) * 64]);
            gl2lds16(&Wz[(size_t)(o0 + row) * HID + k0 + c8 * 8],
                     (void*)&Wh[(w * 32 + e * 8) * 64]);
        }
        __syncthreads();

        #pragma unroll
        for (int ks = 0; ks < 2; ks++) {
            s8v xf[4], yf[4];
            #pragma unroll
            for (int tt = 0; tt < 4; tt++) {
                const int xr  = x0 + tt * 16 + col;
                const int xc8 = (ks * 4 + quad) ^ (xr & 7);
                xf[tt] = *(const s8v*)&Xs[xr * 64 + xc8 * 8];
                const int yr  = y0 + tt * 16 + col;
                const int yc8 = (ks * 4 + quad) ^ (yr & 7);
                yf[tt] = *(const s8v*)&Ys[yr * 64 + yc8 * 8];
            }
            #pragma unroll
            for (int xt = 0; xt < 4; xt++)
                #pragma unroll
                for (int yt = 0; yt < 4; yt++)
                    acc[xt * 4 + yt] = mfma16(xf[xt], yf[yt], acc[xt * 4 + yt]);
        }
    }

    if (z < 2) {
        ushort_t* dst = (z == 0) ? Qo : Ko;
        #pragma unroll
        for (int xt = 0; xt < 4; xt++) {
            const int ob = o0 + x0 + xt * 16 + quad * 4;
            const int h  = ob >> 6;
            const int d0 = ob & 63;
            const float4 bv4 = *(const float4*)&bias[ob];
            #pragma unroll
            for (int yt = 0; yt < 4; yt++) {
                const int m  = m0 + y0 + yt * 16 + col;
                const int bb = m >> 11;
                const int ii = m & (N - 1);
                f4v a = acc[xt * 4 + yt];
                ushort4 pk;
                pk.x = f2bf(a[0] + bv4.x);
                pk.y = f2bf(a[1] + bv4.y);
                pk.z = f2bf(a[2] + bv4.z);
                pk.w = f2bf(a[3] + bv4.w);
                *(ushort4*)&dst[(((size_t)bb * H + h) * N + ii) * D + d0] = pk;
            }
        }
    } else {
        #pragma unroll
        for (int yt = 0; yt < 4; yt++) {
            const int o = o0 + y0 + yt * 16 + col;
            const int h = o >> 6;
            const int d = o & 63;
            const float bs = bias[o];
            #pragma unroll
            for (int xt = 0; xt < 4; xt++) {
                const int m  = m0 + x0 + xt * 16 + quad * 4;
                const int bb = m >> 11;
                const int ib = m & (N - 1);
                f4v a = acc[xt * 4 + yt];
                ushort4 pk;
                pk.x = f2bf(a[0] + bs);
                pk.y = f2bf(a[1] + bs);
                pk.z = f2bf(a[2] + bs);
                pk.w = f2bf(a[3] + bs);
                *(ushort4*)&Vt[(((size_t)bb * H + h) * D + d) * N + ib] = pk;
            }
        }
    }
}

// ---------------------------------------------------------------------------
// Fused relative attention v2: no-max softmax (scores bounded), deferred
// l-reduction, diagonal-transposed SbT gather, Res/Rb ring (stage 64 new
// rows/tile), register-prefetch staging pipeline, distributed row-64 dot.
// grid: (N/64, H, B)  block: 256 (4 waves), wave w owns q rows 16w..16w+15.
// ---------------------------------------------------------------------------
__global__ __launch_bounds__(256) void attn_mfma_kernel(
    const ushort_t* __restrict__ Qb, const ushort_t* __restrict__ Kb,
    const ushort_t* __restrict__ Vt, const ushort_t* __restrict__ reb,
    const float* __restrict__ rbt, const float* __restrict__ rwb_g,
    float* __restrict__ out)
{
    const int i0 = blockIdx.x * 64;
    const int h  = blockIdx.y;
    const int b  = blockIdx.z;
    const int bh = b * H + h;

    const ushort_t* Qbh = Qb + (size_t)bh * N * D;
    const ushort_t* Kbh = Kb + (size_t)bh * N * D;
    const ushort_t* Vbh = Vt + (size_t)bh * D * N;   // [d][n]
    const ushort_t* reh = reb + (size_t)h * N * D;   // [s][d]
    const float*    rbh = rbt + (size_t)h * N;

    // LDS: Ks 9216 | Vs 9216 | Res 18432 | SbT 13056 | Rb 512 | QL/Ps 9216
    __shared__ __align__(16) char smem[59648];
    ushort_t (*Ks)[72]  = (ushort_t(*)[72])(smem + 0);       // 64x72 [key][d]
    ushort_t (*Vs)[72]  = (ushort_t(*)[72])(smem + 9216);    // 64x72 [d][key]
    ushort_t (*Res)[72] = (ushort_t(*)[72])(smem + 18432);   // 128x72 ring
    ushort_t (*SbT)[68] = (ushort_t(*)[68])(smem + 36864);   // 96x68 [u+rho-48][rho]
    float*    Rb        = (float*)(smem + 49920);            // 128 ring
    ushort_t (*QL)[72]  = (ushort_t(*)[72])(smem + 50432);   // 64x72 (init only)
    ushort_t (*PsAll)[72] = (ushort_t(*)[72])(smem + 50432); // Ps aliases QL

    const int t    = threadIdx.x;
    const int lane = t & 63;
    const int w    = t >> 6;
    const int quad = lane >> 4;
    const int col  = lane & 15;
    ushort_t (*Ps)[72] = PsAll + w * 16;

    // ---- init: Q rows into QL; q64 row into regs ----
    #pragma unroll
    for (int e = 0; e < 2; e++) {
        const int idx = t + e * 256;
        const int r   = idx >> 3;
        const int d8  = (idx & 7) * 8;
        *(s8v*)&QL[r][d8] = *(const s8v*)&Qbh[(size_t)(i0 + r) * D + d8];
    }
    const int sub = t & 3;             // row-64 dot: 16-d chunk index
    s8v q64a = {0,0,0,0,0,0,0,0}, q64b = {0,0,0,0,0,0,0,0};
    if (i0 + 64 < N) {
        q64a = *(const s8v*)&Qbh[(size_t)(i0 + 64) * D + sub * 16];
        q64b = *(const s8v*)&Qbh[(size_t)(i0 + 64) * D + sub * 16 + 8];
    }
    __syncthreads();

    s8v qr[2], qw[2];
    #pragma unroll
    for (int ks = 0; ks < 2; ks++) {
        qr[ks] = *(s8v*)&QL[16 * w + col][ks * 32 + quad * 8];
        float4 r0 = *(const float4*)&rwb_g[h * D + ks * 32 + quad * 8];
        float4 r1 = *(const float4*)&rwb_g[h * D + ks * 32 + quad * 8 + 4];
        const float rv[8] = {r0.x, r0.y, r0.z, r0.w, r1.x, r1.y, r1.z, r1.w};
        s8v qq;
        #pragma unroll
        for (int j = 0; j < 8; j++)
            qq[j] = (short)f2bf(bf2f(qr[ks][j]) + rv[j]);
        qw[ks] = qq;
    }

    // ---- prologue: stage tile 0 (K, V, full 128-row Res window, Rb) ----
    {
        #pragma unroll
        for (int e = 0; e < 2; e++) {
            const int idx = t + e * 256;
            const int r   = idx >> 3;
            const int d8  = (idx & 7) * 8;
            *(s8v*)&Ks[r][d8] = *(const s8v*)&Kbh[(size_t)r * D + d8];
            *(s8v*)&Vs[r][d8] = *(const s8v*)&Vbh[(size_t)r * N + d8];
        }
        #pragma unroll
        for (int e = 0; e < 4; e++) {
            const int idx = t + e * 256;
            const int u   = idx >> 3;
            const int d8  = (idx & 7) * 8;
            const int src = clampsrc(u - i0 - 65);
            *(s8v*)&Res[u][d8] = *(const s8v*)&reh[(size_t)src * D + d8];
        }
        if (t < 128) Rb[t] = rbh[clampsrc(t - i0 - 65)];
    }

    f4v Oacc[4];
    #pragma unroll
    for (int dt = 0; dt < 4; dt++) Oacc[dt] = (f4v){0.f, 0.f, 0.f, 0.f};
    float lacc[4] = {0.f, 0.f, 0.f, 0.f};

    const int u0w  = 48 - 16 * w;
    const int u64  = 16 * w + (lane >> 2);   // row-64 dot: this thread's u
    int off = 0;                              // ring offset = 64*s & 127

    for (int s = 0; s < 32; ++s) {
        const int j0 = s * 64;
        __syncthreads();   // tile s staged & previous tile fully consumed

        // ---- prefetch tile s+1 into regs (latency overlaps compute) ----
        s8v pk[2], pv[2], pr[2];
        float prb = 0.f;
        const int jn = j0 + 64;
        if (s < 31) {
            #pragma unroll
            for (int e = 0; e < 2; e++) {
                const int idx = t + e * 256;
                const int r   = idx >> 3;
                const int d8  = (idx & 7) * 8;
                pk[e] = *(const s8v*)&Kbh[(size_t)(jn + r) * D + d8];
                pv[e] = *(const s8v*)&Vbh[(size_t)r * N + jn + d8];
                const int src = clampsrc(jn - i0 - 1 + r);
                pr[e] = *(const s8v*)&reh[(size_t)src * D + d8];
            }
            if (t < 64) prb = rbh[clampsrc(jn - i0 - 1 + t)];
        }

        // ---- AC: Qw @ K^T ----
        f4v acc[4];
        #pragma unroll
        for (int tile = 0; tile < 4; tile++) {
            acc[tile] = (f4v){0.f, 0.f, 0.f, 0.f};
            #pragma unroll
            for (int ks = 0; ks < 2; ks++) {
                s8v kb = *(s8v*)&Ks[tile * 16 + col][ks * 32 + quad * 8];
                acc[tile] = mfma16(qw[ks], kb, acc[tile]);
            }
        }
        // ---- BD product -> diagonal SbT (ring-indexed Res reads) ----
        #pragma unroll
        for (int tt = 0; tt < 5; tt++) {
            const int u = u0w + tt * 16 + col;
            f4v sb = (f4v){0.f, 0.f, 0.f, 0.f};
            #pragma unroll
            for (int ks = 0; ks < 2; ks++) {
                s8v rb8 = *(s8v*)&Res[(u + off) & 127][ks * 32 + quad * 8];
                sb = mfma16(qr[ks], rb8, sb);
            }
            const float rbv = Rb[(u + off) & 127];
            #pragma unroll
            for (int reg = 0; reg < 4; reg++) {
                const int rho = 16 * w + quad * 4 + reg;
                SbT[tt * 16 + col + quad * 4 + reg][rho] = f2bf(sb[reg] + rbv);
            }
        }
        // ---- row 64 (distributed): SbT[u+16][64] = q64 . res(u) + rb ----
        {
            float part = 0.f;
            const int rp = (u64 + off) & 127;
            s8v r0 = *(s8v*)&Res[rp][sub * 16];
            s8v r1 = *(s8v*)&Res[rp][sub * 16 + 8];
            #pragma unroll
            for (int j = 0; j < 8; j++) {
                part += bf2f(q64a[j]) * bf2f(r0[j]);
                part += bf2f(q64b[j]) * bf2f(r1[j]);
            }
            part += __shfl_xor(part, 1, 64);
            part += __shfl_xor(part, 2, 64);
            if (sub == 0)
                SbT[u64 + 16][64] = f2bf(part + Rb[rp]);
        }
        __syncthreads();   // SbT complete (cross-wave boundary rows)

        // ---- gather (rel_shift) + no-max softmax ----
        float p[4][4];
        const int rbase = 16 * w + quad * 4;
        #pragma unroll
        for (int tile = 0; tile < 4; tile++) {
            const int cr   = tile * 16 + col + 16;   // SbT row = cp + 16
            ushort4 q4a = *(ushort4*)&SbT[cr][rbase];
            ushort_t b4 = SbT[cr][rbase + 4];
            const int tr0 = (j0 + tile * 16 + col) - (i0 + rbase);
            #pragma unroll
            for (int reg = 0; reg < 4; reg++) {
                const int trel = tr0 - reg;
                float bd = 0.f;
                if (trel != 1) {
                    const int ix = reg + (trel >= 2 ? 1 : 0);
                    ushort_t v;
                    if (ix == 0)      v = q4a.x;
                    else if (ix == 1) v = q4a.y;
                    else if (ix == 2) v = q4a.z;
                    else if (ix == 3) v = q4a.w;
                    else              v = b4;
                    bd = bf2f((short)v);
                }
                const float e = __expf((acc[tile][reg] + bd) * 0.125f);
                p[tile][reg] = e;
                lacc[reg] += e;
            }
        }
        // ---- P -> LDS (wave-private), PV ----
        #pragma unroll
        for (int tile = 0; tile < 4; tile++)
            #pragma unroll
            for (int reg = 0; reg < 4; reg++)
                Ps[quad * 4 + reg][tile * 16 + col] = f2bf(p[tile][reg]);
        __asm__ volatile("s_waitcnt lgkmcnt(0)" ::: "memory");
        #pragma unroll
        for (int dt = 0; dt < 4; dt++) {
            #pragma unroll
            for (int ks = 0; ks < 2; ks++) {
                s8v pf = *(s8v*)&Ps[col][ks * 32 + quad * 8];
                s8v vf = *(s8v*)&Vs[dt * 16 + col][ks * 32 + quad * 8];
                Oacc[dt] = mfma16(pf, vf, Oacc[dt]);
            }
        }
        __syncthreads();   // all reads of tile s done

        // ---- write prefetched tile s+1 ----
        if (s < 31) {
            #pragma unroll
            for (int e = 0; e < 2; e++) {
                const int idx = t + e * 256;
                const int r   = idx >> 3;
                const int d8  = (idx & 7) * 8;
                *(s8v*)&Ks[r][d8] = pk[e];
                *(s8v*)&Vs[r][d8] = pv[e];
                *(s8v*)&Res[(r + off) & 127][d8] = pr[e];
            }
            if (t < 64) Rb[(t + off) & 127] = prb;
            off = (off + 64) & 127;
        }
    }

    // ---- final l reduction (16 lanes per row) + epilogue ----
    #pragma unroll
    for (int reg = 0; reg < 4; reg++) {
        #pragma unroll
        for (int msk = 1; msk < 16; msk <<= 1)
            lacc[reg] += __shfl_xor(lacc[reg], msk, 64);
    }
    #pragma unroll
    for (int reg = 0; reg < 4; reg++) {
        const float inv = 1.f / lacc[reg];
        const int row = i0 + 16 * w + quad * 4 + reg;
        const size_t base = ((size_t)b * N + row) * HID + h * D;
        #pragma unroll
        for (int dt = 0; dt < 4; dt++)
            out[base + dt * 16 + col] = Oacc[dt][reg] * inv;
    }
}

// ---------------------------------------------------------------------------
extern "C" void kernel_launch(void* const* d_in, const int* in_sizes, int n_in,
                              void* d_out, int out_size, void* d_ws, size_t ws_size,
                              hipStream_t stream)
{
    (void)in_sizes; (void)n_in; (void)out_size; (void)ws_size;
    const float* hs   = (const float*)d_in[0];
    const float* remb = (const float*)d_in[1];
    const float* rwb  = (const float*)d_in[2];
    const float* rb   = (const float*)d_in[3];
    const float* Wq   = (const float*)d_in[4];
    const float* bq   = (const float*)d_in[5];
    const float* Wk   = (const float*)d_in[6];
    const float* bk   = (const float*)d_in[7];
    const float* Wv   = (const float*)d_in[8];
    const float* bv   = (const float*)d_in[9];
    float* out = (float*)d_out;

    ushort_t* Qb  = (ushort_t*)d_ws;
    ushort_t* Kb  = Qb + QKV_ELEMS;
    ushort_t* Vt  = Kb + QKV_ELEMS;
    ushort_t* reb = Vt + QKV_ELEMS;
    float*    rbt = (float*)(reb + H * N * D);
    ushort_t* hsb = (ushort_t*)(rbt + H * N);
    ushort_t* Wb  = hsb + (size_t)M * HID;

    convert_kernel<<<CVT_C3 / 256, 256, 0, stream>>>(
        hs, Wq, Wk, Wv, remb, rb, hsb, Wb, reb, rbt);
    qkv_mfma_kernel<<<dim3(M / 128, HID / 128, 3), 256, 0, stream>>>(
        hsb, Wb, bq, bk, bv, Qb, Kb, Vt);
    attn_mfma_kernel<<<dim3(N / 64, H, B), 256, 0, stream>>>(
        Qb, Kb, Vt, reb, rbt, rwb, out);
}